// Round 7
// baseline (240.541 us; speedup 1.0000x reference)
//
#include <hip/hip_runtime.h>

// ---------------------------------------------------------------------------
// GCN 3-layer forward. Key invariant: every gather input is PRE-SCALED by
// dinv (H' = H*dinv[row], folded into producer epilogues), so aggregation is
// an UNWEIGHTED sum:  Ahat(H)[i] = dinv[i] * (sum_e H'[src_e] + H'[i]).
// No per-edge dinv gather, no per-edge multiply.
//
//   CSR: hist(dst>>8) -> scan -> 2-pass chunked bucket scatter (packed
//        pk=(dst<<16)|src, no scratch) -> per-bucket LDS sort
//   L1: H1' = (x@W1)*dinv                  [gemm1, 3-prod MFMA]
//   A : AGG1 = relu(di*(S(H1'))+b1) in LDS ; H2' = (AGG1@W2)*dinv  [fusedA]
//   g2: H3' = relu(di*(S(H2'))+b2)*dinv    [gather2]
//   B : T = di*S(H3') in LDS ; out = T@W3 + b3                     [fusedB]
// MFMA 16x16x32 bf16; A[row=l&15][k=(l>>4)*8+j], B[k=(l>>4)*8+j][col=l&15],
// C/D col=l&15,row=(l>>4)*4+r (learn_hip m89).
// ---------------------------------------------------------------------------

#define DEV_INLINE __device__ __forceinline__

typedef unsigned int uint;
typedef unsigned short ushort;
typedef __attribute__((ext_vector_type(8))) short bf16x8;
typedef __attribute__((ext_vector_type(4))) float f32x4;

// ---- bf16 helpers ----
static DEV_INLINE uint f2bf_rne(float f) {
    uint u = __float_as_uint(f);
    return (u + 0x7FFFu + ((u >> 16) & 1u)) >> 16;
}
static DEV_INLINE float bflo(uint u) { return __uint_as_float(u << 16); }
static DEV_INLINE float bfhi(uint u) { return __uint_as_float(u & 0xFFFF0000u); }

static DEV_INLINE void add8(float4& a, float4& b, const uint4& v) {
    a.x += bflo(v.x); a.y += bfhi(v.x);
    a.z += bflo(v.y); a.w += bfhi(v.y);
    b.x += bflo(v.z); b.y += bfhi(v.z);
    b.z += bflo(v.w); b.w += bfhi(v.w);
}

static DEV_INLINE void split8(const float4& x0, const float4& x1, bf16x8& ah, bf16x8& al) {
    float xs[8] = {x0.x, x0.y, x0.z, x0.w, x1.x, x1.y, x1.z, x1.w};
#pragma unroll
    for (int j = 0; j < 8; ++j) {
        uint u = __float_as_uint(xs[j]);
        ah[j] = (short)(u >> 16);
        float r = xs[j] - __uint_as_float(u & 0xFFFF0000u);
        al[j] = (short)(__float_as_uint(r) >> 16);
    }
}

// unweighted gather-sum of bf16 rows: o0/o1 carry the self term on entry.
// FW = uints per row. 8-edge unroll, 4 accumulator pairs for MLP.
template<int FW>
static DEV_INLINE void gather_sum(const uint* __restrict__ H, const ushort* __restrict__ perm,
                                  int beg, int end, int lane, float4& o0, float4& o1)
{
    float4 A0 = o0, A1 = o1;
    float4 B0 = make_float4(0.f,0.f,0.f,0.f), B1 = B0, C0 = B0, C1 = B0, D0 = B0, D1 = B0;
    const uint4* Hv = reinterpret_cast<const uint4*>(H);
    int e = beg;
    for (; e + 8 <= end; e += 8) {
        int s0 = perm[e];     int s1 = perm[e + 1];
        int s2 = perm[e + 2]; int s3 = perm[e + 3];
        int s4 = perm[e + 4]; int s5 = perm[e + 5];
        int s6 = perm[e + 6]; int s7 = perm[e + 7];
        uint4 v0 = Hv[(size_t)s0 * (FW / 4) + lane];
        uint4 v1 = Hv[(size_t)s1 * (FW / 4) + lane];
        uint4 v2 = Hv[(size_t)s2 * (FW / 4) + lane];
        uint4 v3 = Hv[(size_t)s3 * (FW / 4) + lane];
        uint4 v4 = Hv[(size_t)s4 * (FW / 4) + lane];
        uint4 v5 = Hv[(size_t)s5 * (FW / 4) + lane];
        uint4 v6 = Hv[(size_t)s6 * (FW / 4) + lane];
        uint4 v7 = Hv[(size_t)s7 * (FW / 4) + lane];
        add8(A0, A1, v0); add8(B0, B1, v1); add8(C0, C1, v2); add8(D0, D1, v3);
        add8(A0, A1, v4); add8(B0, B1, v5); add8(C0, C1, v6); add8(D0, D1, v7);
    }
    for (; e < end; ++e) {
        uint4 v = Hv[(size_t)perm[e] * (FW / 4) + lane];
        add8(A0, A1, v);
    }
    o0.x = A0.x + B0.x + C0.x + D0.x; o0.y = A0.y + B0.y + C0.y + D0.y;
    o0.z = A0.z + B0.z + C0.z + D0.z; o0.w = A0.w + B0.w + C0.w + D0.w;
    o1.x = A1.x + B1.x + C1.x + D1.x; o1.y = A1.y + B1.y + C1.y + D1.y;
    o1.z = A1.z + B1.z + C1.z + D1.z; o1.w = A1.w + B1.w + C1.w + D1.w;
}

// ------------------------- CSR: two-level bucket sort ------------------------

__global__ __launch_bounds__(256) void hist_coarse_kernel(
    const int* __restrict__ dst, int* __restrict__ cnt196, int E, int NBK)
{
    __shared__ int h[256];
    if ((int)threadIdx.x < NBK) h[threadIdx.x] = 0;
    __syncthreads();
    for (int i = blockIdx.x * blockDim.x + threadIdx.x; i < E; i += gridDim.x * blockDim.x)
        atomicAdd(&h[dst[i] >> 8], 1);
    __syncthreads();
    if ((int)threadIdx.x < NBK) {
        int v = h[threadIdx.x];
        if (v) atomicAdd(&cnt196[threadIdx.x], v);
    }
}

__global__ void scan_coarse_kernel(const int* __restrict__ cnt196, int* __restrict__ base196,
                                   int* __restrict__ cursor196, int* __restrict__ rowptr,
                                   int NBK, int N, int E)
{
    __shared__ int buf[256];
    const int tid = threadIdx.x;
    int v = (tid < NBK) ? cnt196[tid] : 0;
    buf[tid] = v;
    __syncthreads();
#pragma unroll
    for (int ofs = 1; ofs < 256; ofs <<= 1) {
        int t = (tid >= ofs) ? buf[tid - ofs] : 0;
        __syncthreads();
        buf[tid] += t;
        __syncthreads();
    }
    if (tid < NBK) {
        int b = buf[tid] - v;
        base196[tid] = b;
        cursor196[tid] = b;
    }
    if (tid == 0) rowptr[N] = E;
}

// two-pass chunked scatter (no register-array scratch): pass1 LDS-hist,
// claim ranges, pass2 re-read (L2-hit) and write packed edges densely.
__global__ __launch_bounds__(256) void scatter_coarse_kernel(
    const int* __restrict__ src, const int* __restrict__ dst,
    int* __restrict__ cursor196, uint* __restrict__ pkg, int E, int NBK)
{
    __shared__ int histL[256];
    __shared__ int baseL[256];
    const int tid = threadIdx.x;
    const int c0  = blockIdx.x * 2048;
    if (tid < NBK) histL[tid] = 0;
    __syncthreads();
#pragma unroll
    for (int k = 0; k < 8; ++k) {
        int idx = c0 + k * 256 + tid;
        if (idx < E) atomicAdd(&histL[dst[idx] >> 8], 1);
    }
    __syncthreads();
    if (tid < NBK) {
        int h = histL[tid];
        baseL[tid] = (h > 0) ? atomicAdd(&cursor196[tid], h) : 0;
        histL[tid] = 0;
    }
    __syncthreads();
#pragma unroll
    for (int k = 0; k < 8; ++k) {
        int idx = c0 + k * 256 + tid;
        if (idx < E) {
            int d = dst[idx];
            int b = d >> 8;
            int pos = baseL[b] + atomicAdd(&histL[b], 1);
            pkg[pos] = ((uint)d << 16) | (uint)(src[idx] & 0xFFFF);
        }
    }
}

__global__ __launch_bounds__(256) void build_fine_kernel(
    const uint* __restrict__ pkg, const int* __restrict__ cnt196,
    const int* __restrict__ base196, int* __restrict__ rowptr,
    float* __restrict__ dinv, ushort* __restrict__ perm, int N)
{
    __shared__ uint   pkL[8192];
    __shared__ ushort outS[8192];
    __shared__ int hist[256];
    __shared__ int buf[256];
    const int b   = blockIdx.x;
    const int tid = threadIdx.x;
    const int base = base196[b];
    int nE = cnt196[b];
    if (nE > 8192) nE = 8192;

    hist[tid] = 0;
    __syncthreads();
    for (int i = tid; i < nE; i += 256) {
        uint pk = pkg[base + i];
        pkL[i] = pk;
        atomicAdd(&hist[(pk >> 16) & 255], 1);
    }
    __syncthreads();

    int cnt = hist[tid];
    buf[tid] = cnt;
    __syncthreads();
#pragma unroll
    for (int ofs = 1; ofs < 256; ofs <<= 1) {
        int t = (tid >= ofs) ? buf[tid - ofs] : 0;
        __syncthreads();
        buf[tid] += t;
        __syncthreads();
    }
    int excl = buf[tid] - cnt;
    int node = b * 256 + tid;
    if (node < N) {
        rowptr[node] = base + excl;
        dinv[node]   = rsqrtf((float)(cnt + 1));   // +1 self-loop
    }
    hist[tid] = excl;
    __syncthreads();
    for (int i = tid; i < nE; i += 256) {
        uint pk = pkL[i];
        int d = (pk >> 16) & 255;
        int pos = atomicAdd(&hist[d], 1);
        outS[pos] = (ushort)(pk & 0xFFFFu);
    }
    __syncthreads();
    for (int i = tid; i < nE; i += 256) perm[base + i] = outS[i];
}

// ------------------------- W fragment prep (bf16 split) ---------------------

template<int K, int NOUT>
static DEV_INLINE void prep_one(const float* __restrict__ W,
                                ushort* __restrict__ Wh, ushort* __restrict__ Wl, int id) {
    constexpr int C = NOUT / 16;
    int lane = id & 63;
    int tc   = id >> 6;
    int c = tc % C, t = tc / C;
    int krow = t * 32 + (lane >> 4) * 8;
    int col  = c * 16 + (lane & 15);
#pragma unroll
    for (int j = 0; j < 8; ++j) {
        float w = W[(size_t)(krow + j) * NOUT + col];
        uint u = __float_as_uint(w);
        Wh[(size_t)id * 8 + j] = (ushort)(u >> 16);
        float r = w - __uint_as_float(u & 0xFFFF0000u);
        Wl[(size_t)id * 8 + j] = (ushort)(__float_as_uint(r) >> 16);
    }
}

__global__ void prep_wfrag_all_kernel(
    const float* __restrict__ W1, const float* __restrict__ W2, const float* __restrict__ W3,
    ushort* w1h, ushort* w1l, ushort* w2h, ushort* w2l, ushort* w3h, ushort* w3l)
{
    int id = blockIdx.x * 256 + threadIdx.x;
    if (id < 2048)       prep_one<128, 128>(W1, w1h, w1l, id);
    else if (id < 3072)  prep_one<128, 64>(W2, w2h, w2l, id - 2048);
    else if (id < 4096)  prep_one<64, 128>(W3, w3h, w3l, id - 3072);
}

// ------------------------------ gemm1 ---------------------------------------
// H1'[N,128] (bf16) = (x[N,128] @ W1) * dinv[row].  f32 A, 3-product MFMA.

__global__ __launch_bounds__(256) void gemm1_kernel(
    const float* __restrict__ A, const ushort* __restrict__ Whf, const ushort* __restrict__ Wlf,
    const float* __restrict__ dinv, ushort* __restrict__ Cout, int N)
{
    constexpr int C = 8, T = 4, K = 128, NOUT = 128;
    const int tid  = threadIdx.x;
    const int w    = tid >> 6;
    const int lane = tid & 63;
    const int row0 = blockIdx.x * 64 + w * 16;
    const int arow  = row0 + (lane & 15);
    const int arowc = (arow < N) ? arow : (N - 1);
    const int lq    = (lane >> 4);

    const bf16x8* WH = reinterpret_cast<const bf16x8*>(Whf);
    const bf16x8* WL = reinterpret_cast<const bf16x8*>(Wlf);

    f32x4 acc[C];
#pragma unroll
    for (int c = 0; c < C; ++c) acc[c] = (f32x4){0.f, 0.f, 0.f, 0.f};

#pragma unroll
    for (int t = 0; t < T; ++t) {
        const float* ap = A + (size_t)arowc * K + t * 32 + lq * 8;
        float4 x0 = *reinterpret_cast<const float4*>(ap);
        float4 x1 = *reinterpret_cast<const float4*>(ap + 4);
        bf16x8 ah, al;
        split8(x0, x1, ah, al);
#pragma unroll
        for (int c = 0; c < C; ++c) {
            bf16x8 bh = WH[(t * C + c) * 64 + lane];
            bf16x8 bl = WL[(t * C + c) * 64 + lane];
            acc[c] = __builtin_amdgcn_mfma_f32_16x16x32_bf16(ah, bh, acc[c], 0, 0, 0);
            acc[c] = __builtin_amdgcn_mfma_f32_16x16x32_bf16(al, bh, acc[c], 0, 0, 0);
            acc[c] = __builtin_amdgcn_mfma_f32_16x16x32_bf16(ah, bl, acc[c], 0, 0, 0);
        }
    }

    const int rbase = (lane >> 4) * 4;
    const int ccol  = (lane & 15);
#pragma unroll
    for (int r = 0; r < 4; ++r) {
        int row = row0 + rbase + r;
        if (row < N) {
            float di = dinv[row];
#pragma unroll
            for (int c = 0; c < C; ++c) {
                int col = c * 16 + ccol;
                Cout[(size_t)row * NOUT + col] = (ushort)f2bf_rne(acc[c][r] * di);
            }
        }
    }
}

// --------------------- fusedA: AGG1(LDS) + gemm2 ----------------------------
// gather: AGG1[i,:] = relu(di*(S(H1')+H1'[i]) + b1) -> LDS f32 [64][132]
// gemm:   H2'[i,:]  = (AGG1 @ W2) * dinv[i] -> bf16

__global__ __launch_bounds__(256) void fused_agg1_gemm2_kernel(
    const uint* __restrict__ H1, const int* __restrict__ rowptr,
    const ushort* __restrict__ perm, const float* __restrict__ dinv,
    const float* __restrict__ b1, const ushort* __restrict__ w2h,
    const ushort* __restrict__ w2l, ushort* __restrict__ H2, int N)
{
    __shared__ float As[64][132];
    const int tid  = threadIdx.x;
    const int row0 = blockIdx.x * 64;

    {   // ---- gather phase: 16 groups x 16 lanes; 4 passes ----
        const int lg = tid & 15;
        const int g  = tid >> 4;
        const float4* b4 = reinterpret_cast<const float4*>(b1);
        float4 bb0 = b4[lg * 2], bb1 = b4[lg * 2 + 1];
#pragma unroll
        for (int p = 0; p < 4; ++p) {
            int nl = p * 16 + g;
            int node = row0 + nl;
            int nodec = (node < N) ? node : (N - 1);
            int beg = rowptr[nodec], end = rowptr[nodec + 1];
            float di = dinv[nodec];
            float4 o0 = make_float4(0.f,0.f,0.f,0.f), o1 = o0;
            uint4 sv = reinterpret_cast<const uint4*>(H1 + (size_t)nodec * 64)[lg];
            add8(o0, o1, sv);
            gather_sum<64>(H1, perm, beg, end, lg, o0, o1);
            float4 r0, r1;
            r0.x = fmaxf(fmaf(di, o0.x, bb0.x), 0.f);
            r0.y = fmaxf(fmaf(di, o0.y, bb0.y), 0.f);
            r0.z = fmaxf(fmaf(di, o0.z, bb0.z), 0.f);
            r0.w = fmaxf(fmaf(di, o0.w, bb0.w), 0.f);
            r1.x = fmaxf(fmaf(di, o1.x, bb1.x), 0.f);
            r1.y = fmaxf(fmaf(di, o1.y, bb1.y), 0.f);
            r1.z = fmaxf(fmaf(di, o1.z, bb1.z), 0.f);
            r1.w = fmaxf(fmaf(di, o1.w, bb1.w), 0.f);
            *reinterpret_cast<float4*>(&As[nl][lg * 8])     = r0;
            *reinterpret_cast<float4*>(&As[nl][lg * 8 + 4]) = r1;
        }
    }
    __syncthreads();

    // ---- gemm phase: K=128, NOUT=64, A from LDS (3-prod) ----
    const int w    = tid >> 6;
    const int lane = tid & 63;
    const int ar   = w * 16 + (lane & 15);
    const int lq   = lane >> 4;
    const bf16x8* WH = reinterpret_cast<const bf16x8*>(w2h);
    const bf16x8* WL = reinterpret_cast<const bf16x8*>(w2l);

    f32x4 acc[4];
#pragma unroll
    for (int c = 0; c < 4; ++c) acc[c] = (f32x4){0.f, 0.f, 0.f, 0.f};

#pragma unroll
    for (int t = 0; t < 4; ++t) {
        float4 x0 = *reinterpret_cast<const float4*>(&As[ar][t * 32 + lq * 8]);
        float4 x1 = *reinterpret_cast<const float4*>(&As[ar][t * 32 + lq * 8 + 4]);
        bf16x8 ah, al;
        split8(x0, x1, ah, al);
#pragma unroll
        for (int c = 0; c < 4; ++c) {
            bf16x8 bh = WH[(t * 4 + c) * 64 + lane];
            bf16x8 bl = WL[(t * 4 + c) * 64 + lane];
            acc[c] = __builtin_amdgcn_mfma_f32_16x16x32_bf16(ah, bh, acc[c], 0, 0, 0);
            acc[c] = __builtin_amdgcn_mfma_f32_16x16x32_bf16(al, bh, acc[c], 0, 0, 0);
            acc[c] = __builtin_amdgcn_mfma_f32_16x16x32_bf16(ah, bl, acc[c], 0, 0, 0);
        }
    }

    const int rbase = (lane >> 4) * 4;
    const int ccol  = (lane & 15);
#pragma unroll
    for (int r = 0; r < 4; ++r) {
        int grow = row0 + w * 16 + rbase + r;
        if (grow < N) {
            float di = dinv[grow];
#pragma unroll
            for (int c = 0; c < 4; ++c) {
                int col = c * 16 + ccol;
                H2[(size_t)grow * 64 + col] = (ushort)f2bf_rne(acc[c][r] * di);
            }
        }
    }
}

// ------------------------------ gather2 -------------------------------------
// H3'[i,:] = relu(di*(S(H2')+H2'[i]) + b2) * di   (bf16 out)

__global__ __launch_bounds__(256) void gather2_kernel(
    const uint* __restrict__ H, const int* __restrict__ rowptr,
    const ushort* __restrict__ perm, const float* __restrict__ dinv,
    const float* __restrict__ bias, ushort* __restrict__ OUT, int N)
{
    constexpr int GROUP = 8, FW = 32, NPB = 32;
    const int lane = threadIdx.x % GROUP;
    const int g    = threadIdx.x / GROUP;
    const int node = blockIdx.x * NPB + g;
    if (node >= N) return;

    const int beg = rowptr[node];
    const int end = rowptr[node + 1];
    const float di = dinv[node];

    float4 o0 = make_float4(0.f,0.f,0.f,0.f), o1 = o0;
    uint4 sv = reinterpret_cast<const uint4*>(H + (size_t)node * FW)[lane];
    add8(o0, o1, sv);
    gather_sum<FW>(H, perm, beg, end, lane, o0, o1);

    const float4* b4 = reinterpret_cast<const float4*>(bias);
    float4 c0 = b4[lane * 2], c1 = b4[lane * 2 + 1];
    float v[8];
    v[0] = fmaxf(fmaf(di, o0.x, c0.x), 0.f) * di;
    v[1] = fmaxf(fmaf(di, o0.y, c0.y), 0.f) * di;
    v[2] = fmaxf(fmaf(di, o0.z, c0.z), 0.f) * di;
    v[3] = fmaxf(fmaf(di, o0.w, c0.w), 0.f) * di;
    v[4] = fmaxf(fmaf(di, o1.x, c1.x), 0.f) * di;
    v[5] = fmaxf(fmaf(di, o1.y, c1.y), 0.f) * di;
    v[6] = fmaxf(fmaf(di, o1.z, c1.z), 0.f) * di;
    v[7] = fmaxf(fmaf(di, o1.w, c1.w), 0.f) * di;
    uint4 u;
    u.x = f2bf_rne(v[0]) | (f2bf_rne(v[1]) << 16);
    u.y = f2bf_rne(v[2]) | (f2bf_rne(v[3]) << 16);
    u.z = f2bf_rne(v[4]) | (f2bf_rne(v[5]) << 16);
    u.w = f2bf_rne(v[6]) | (f2bf_rne(v[7]) << 16);
    reinterpret_cast<uint4*>(OUT + (size_t)node * 64)[lane] = u;
}

// --------------------- fusedB: T(LDS) + gemm3 -------------------------------
// gather: T[i,:] = di*(S(H3')+H3'[i]) -> LDS f32 [64][68]
// gemm:   out = T @ W3 + b3  (f32 out)

__global__ __launch_bounds__(256) void fused_agg3_gemm3_kernel(
    const uint* __restrict__ H3, const int* __restrict__ rowptr,
    const ushort* __restrict__ perm, const float* __restrict__ dinv,
    const ushort* __restrict__ w3h, const ushort* __restrict__ w3l,
    const float* __restrict__ b3, float* __restrict__ out, int N)
{
    __shared__ float Ts[64][68];
    const int tid  = threadIdx.x;
    const int row0 = blockIdx.x * 64;

    {   // ---- gather phase: 32 groups x 8 lanes; 2 passes ----
        const int lg = tid & 7;
        const int g  = tid >> 3;
#pragma unroll
        for (int p = 0; p < 2; ++p) {
            int nl = p * 32 + g;
            int node = row0 + nl;
            int nodec = (node < N) ? node : (N - 1);
            int beg = rowptr[nodec], end = rowptr[nodec + 1];
            float di = dinv[nodec];
            float4 o0 = make_float4(0.f,0.f,0.f,0.f), o1 = o0;
            uint4 sv = reinterpret_cast<const uint4*>(H3 + (size_t)nodec * 32)[lg];
            add8(o0, o1, sv);
            gather_sum<32>(H3, perm, beg, end, lg, o0, o1);
            float4 r0, r1;
            r0.x = di * o0.x; r0.y = di * o0.y; r0.z = di * o0.z; r0.w = di * o0.w;
            r1.x = di * o1.x; r1.y = di * o1.y; r1.z = di * o1.z; r1.w = di * o1.w;
            *reinterpret_cast<float4*>(&Ts[nl][lg * 8])     = r0;
            *reinterpret_cast<float4*>(&Ts[nl][lg * 8 + 4]) = r1;
        }
    }
    __syncthreads();

    // ---- gemm phase: K=64, NOUT=128, A from LDS (3-prod) ----
    const int w    = tid >> 6;
    const int lane = tid & 63;
    const int ar   = w * 16 + (lane & 15);
    const int lq   = lane >> 4;
    const bf16x8* WH = reinterpret_cast<const bf16x8*>(w3h);
    const bf16x8* WL = reinterpret_cast<const bf16x8*>(w3l);

    f32x4 acc[8];
#pragma unroll
    for (int c = 0; c < 8; ++c) acc[c] = (f32x4){0.f, 0.f, 0.f, 0.f};

#pragma unroll
    for (int t = 0; t < 2; ++t) {
        float4 x0 = *reinterpret_cast<const float4*>(&Ts[ar][t * 32 + lq * 8]);
        float4 x1 = *reinterpret_cast<const float4*>(&Ts[ar][t * 32 + lq * 8 + 4]);
        bf16x8 ah, al;
        split8(x0, x1, ah, al);
#pragma unroll
        for (int c = 0; c < 8; ++c) {
            bf16x8 bh = WH[(t * 8 + c) * 64 + lane];
            bf16x8 bl = WL[(t * 8 + c) * 64 + lane];
            acc[c] = __builtin_amdgcn_mfma_f32_16x16x32_bf16(ah, bh, acc[c], 0, 0, 0);
            acc[c] = __builtin_amdgcn_mfma_f32_16x16x32_bf16(al, bh, acc[c], 0, 0, 0);
            acc[c] = __builtin_amdgcn_mfma_f32_16x16x32_bf16(ah, bl, acc[c], 0, 0, 0);
        }
    }

    const int rbase = (lane >> 4) * 4;
    const int ccol  = (lane & 15);
#pragma unroll
    for (int r = 0; r < 4; ++r) {
        int grow = row0 + w * 16 + rbase + r;
        if (grow < N) {
#pragma unroll
            for (int c = 0; c < 8; ++c) {
                int col = c * 16 + ccol;
                out[(size_t)grow * 128 + col] = acc[c][r] + b3[col];
            }
        }
    }
}

// ------------------------------- launcher -----------------------------------

static inline size_t align_up(size_t v, size_t a) { return (v + a - 1) / a * a; }

extern "C" void kernel_launch(void* const* d_in, const int* in_sizes, int n_in,
                              void* d_out, int out_size, void* d_ws, size_t ws_size,
                              hipStream_t stream) {
    const float* x  = (const float*)d_in[0];
    const int*   ei = (const int*)d_in[1];
    const float* W1 = (const float*)d_in[2];
    const float* b1 = (const float*)d_in[3];
    const float* W2 = (const float*)d_in[4];
    const float* b2 = (const float*)d_in[5];
    const float* W3 = (const float*)d_in[6];
    const float* b3 = (const float*)d_in[7];
    float* out = (float*)d_out;

    const int N = in_sizes[0] / 128;   // 50000
    const int E = in_sizes[1] / 2;     // 800000
    const int* src = ei;
    const int* dst = ei + E;
    const int NBK = (N + 255) / 256;   // 196 coarse buckets

    // workspace layout
    char* ws = (char*)d_ws;
    size_t off = 0;
    float* dinv      = (float*)(ws + off); off = align_up(off + (size_t)N * 4, 512);
    int*   rowptr    = (int*)  (ws + off); off = align_up(off + (size_t)(N + 1) * 4, 512);
    int*   cnt196    = (int*)  (ws + off); off = align_up(off + (size_t)NBK * 4, 512);
    int*   base196   = (int*)  (ws + off); off = align_up(off + (size_t)NBK * 4, 512);
    int*   cursor196 = (int*)  (ws + off); off = align_up(off + (size_t)NBK * 4, 512);
    ushort* perm     = (ushort*)(ws + off); off = align_up(off + (size_t)E * 2, 512);
    uint*  pkg       = (uint*) (ws + off); off = align_up(off + (size_t)E * 4, 512);
    uint*  H1bf      = (uint*) (ws + off); off = align_up(off + (size_t)N * 64 * 4, 512);
    uint*  H2bf      = (uint*) (ws + off); off = align_up(off + (size_t)N * 32 * 4, 512);
    uint*  H3bf      = (uint*) (ws + off); off = align_up(off + (size_t)N * 32 * 4, 512);
    ushort* w1h = (ushort*)(ws + off); off = align_up(off + (size_t)128 * 128 * 2, 512);
    ushort* w1l = (ushort*)(ws + off); off = align_up(off + (size_t)128 * 128 * 2, 512);
    ushort* w2h = (ushort*)(ws + off); off = align_up(off + (size_t)128 * 64 * 2, 512);
    ushort* w2l = (ushort*)(ws + off); off = align_up(off + (size_t)128 * 64 * 2, 512);
    ushort* w3h = (ushort*)(ws + off); off = align_up(off + (size_t)64 * 128 * 2, 512);
    ushort* w3l = (ushort*)(ws + off); off = align_up(off + (size_t)64 * 128 * 2, 512);
    (void)ws_size;

    const int TPB = 256;
    dim3 blk(TPB);
    int gRow = (N + 63) / 64;

    // ---- W fragment prep ----
    prep_wfrag_all_kernel<<<16, blk, 0, stream>>>(W1, W2, W3, w1h, w1l, w2h, w2l, w3h, w3l);

    // ---- CSR build ----
    hipMemsetAsync(cnt196, 0, (size_t)NBK * 4, stream);
    hist_coarse_kernel<<<392, blk, 0, stream>>>(dst, cnt196, E, NBK);
    scan_coarse_kernel<<<1, blk, 0, stream>>>(cnt196, base196, cursor196, rowptr, NBK, N, E);
    scatter_coarse_kernel<<<(E + 2047) / 2048, blk, 0, stream>>>(src, dst, cursor196, pkg, E, NBK);
    build_fine_kernel<<<NBK, blk, 0, stream>>>(pkg, cnt196, base196, rowptr, dinv, perm, N);

    // ---- layer pipeline ----
    gemm1_kernel<<<gRow, blk, 0, stream>>>(x, w1h, w1l, dinv, (ushort*)H1bf, N);
    fused_agg1_gemm2_kernel<<<gRow, blk, 0, stream>>>(
        H1bf, rowptr, perm, dinv, b1, w2h, w2l, (ushort*)H2bf, N);
    gather2_kernel<<<(N + 31) / 32, blk, 0, stream>>>(
        H2bf, rowptr, perm, dinv, b2, (ushort*)H3bf, N);
    fused_agg3_gemm3_kernel<<<gRow, blk, 0, stream>>>(
        H3bf, rowptr, perm, dinv, w3h, w3l, b3, out, N);
}

// Round 8
// 238.472 us; speedup vs baseline: 1.0087x; 1.0087x over previous
//
#include <hip/hip_runtime.h>

// ---------------------------------------------------------------------------
// GCN 3-layer forward. Pre-scaled unweighted aggregation:
//   every gather input is H' = H*dinv[row] (folded into producer epilogue),
//   so Ahat(H)[i] = dinv[i] * (sum_{e in(i)} H'[src_e] + H'[i]).
// UNFUSED pipeline (R6 lesson: fusing a latency-bound random gather behind a
// block barrier halves its concurrency; gathers need max oversubscription).
//
//   CSR: hist(dst>>8) -> scan -> 2-pass chunked bucket scatter -> LDS sort
//   gemm1:   H1' = (x@W1)*di            (3-prod MFMA, bf16 out)
//   gather1: AGG1 = relu(di*S(H1')+b1)  (bf16 out)
//   gemm2:   H2' = (AGG1@W2)*di         (2-prod MFMA bf16 A, bf16 out)
//   gather2: H3' = relu(di*S(H2')+b2)*di (bf16 out)
//   gather3: T = di*S(H3')              (f32 out)
//   gemm3:   out = T@W3 + b3            (3-prod MFMA, f32 out)
// MFMA 16x16x32 bf16; A[row=l&15][k=(l>>4)*8+j], B[k=(l>>4)*8+j][col=l&15],
// C/D col=l&15,row=(l>>4)*4+r (learn_hip m89).
// ---------------------------------------------------------------------------

#define DEV_INLINE __device__ __forceinline__

typedef unsigned int uint;
typedef unsigned short ushort;
typedef __attribute__((ext_vector_type(8))) short bf16x8;
typedef __attribute__((ext_vector_type(4))) float f32x4;

// ---- bf16 helpers ----
static DEV_INLINE uint f2bf_rne(float f) {
    uint u = __float_as_uint(f);
    return (u + 0x7FFFu + ((u >> 16) & 1u)) >> 16;
}
static DEV_INLINE float bflo(uint u) { return __uint_as_float(u << 16); }
static DEV_INLINE float bfhi(uint u) { return __uint_as_float(u & 0xFFFF0000u); }

static DEV_INLINE void add8(float4& a, float4& b, const uint4& v) {
    a.x += bflo(v.x); a.y += bfhi(v.x);
    a.z += bflo(v.y); a.w += bfhi(v.y);
    b.x += bflo(v.z); b.y += bfhi(v.z);
    b.z += bflo(v.w); b.w += bfhi(v.w);
}

static DEV_INLINE void split8(const float4& x0, const float4& x1, bf16x8& ah, bf16x8& al) {
    float xs[8] = {x0.x, x0.y, x0.z, x0.w, x1.x, x1.y, x1.z, x1.w};
#pragma unroll
    for (int j = 0; j < 8; ++j) {
        uint u = __float_as_uint(xs[j]);
        ah[j] = (short)(u >> 16);
        float r = xs[j] - __uint_as_float(u & 0xFFFF0000u);
        al[j] = (short)(__float_as_uint(r) >> 16);
    }
}

// unweighted gather-sum of bf16 rows; o0/o1 carry the self term on entry.
// FW = uints per row. 8-edge unroll, 4 accumulator pairs for MLP.
template<int FW>
static DEV_INLINE void gather_sum(const uint* __restrict__ H, const ushort* __restrict__ perm,
                                  int beg, int end, int lane, float4& o0, float4& o1)
{
    float4 A0 = o0, A1 = o1;
    float4 B0 = make_float4(0.f,0.f,0.f,0.f), B1 = B0, C0 = B0, C1 = B0, D0 = B0, D1 = B0;
    const uint4* Hv = reinterpret_cast<const uint4*>(H);
    int e = beg;
    for (; e + 8 <= end; e += 8) {
        int s0 = perm[e];     int s1 = perm[e + 1];
        int s2 = perm[e + 2]; int s3 = perm[e + 3];
        int s4 = perm[e + 4]; int s5 = perm[e + 5];
        int s6 = perm[e + 6]; int s7 = perm[e + 7];
        uint4 v0 = Hv[(size_t)s0 * (FW / 4) + lane];
        uint4 v1 = Hv[(size_t)s1 * (FW / 4) + lane];
        uint4 v2 = Hv[(size_t)s2 * (FW / 4) + lane];
        uint4 v3 = Hv[(size_t)s3 * (FW / 4) + lane];
        uint4 v4 = Hv[(size_t)s4 * (FW / 4) + lane];
        uint4 v5 = Hv[(size_t)s5 * (FW / 4) + lane];
        uint4 v6 = Hv[(size_t)s6 * (FW / 4) + lane];
        uint4 v7 = Hv[(size_t)s7 * (FW / 4) + lane];
        add8(A0, A1, v0); add8(B0, B1, v1); add8(C0, C1, v2); add8(D0, D1, v3);
        add8(A0, A1, v4); add8(B0, B1, v5); add8(C0, C1, v6); add8(D0, D1, v7);
    }
    for (; e < end; ++e) {
        uint4 v = Hv[(size_t)perm[e] * (FW / 4) + lane];
        add8(A0, A1, v);
    }
    o0.x = A0.x + B0.x + C0.x + D0.x; o0.y = A0.y + B0.y + C0.y + D0.y;
    o0.z = A0.z + B0.z + C0.z + D0.z; o0.w = A0.w + B0.w + C0.w + D0.w;
    o1.x = A1.x + B1.x + C1.x + D1.x; o1.y = A1.y + B1.y + C1.y + D1.y;
    o1.z = A1.z + B1.z + C1.z + D1.z; o1.w = A1.w + B1.w + C1.w + D1.w;
}

// ------------------------- CSR: two-level bucket sort ------------------------

__global__ __launch_bounds__(256) void hist_coarse_kernel(
    const int* __restrict__ dst, int* __restrict__ cnt196, int E, int NBK)
{
    __shared__ int h[256];
    if ((int)threadIdx.x < NBK) h[threadIdx.x] = 0;
    __syncthreads();
    for (int i = blockIdx.x * blockDim.x + threadIdx.x; i < E; i += gridDim.x * blockDim.x)
        atomicAdd(&h[dst[i] >> 8], 1);
    __syncthreads();
    if ((int)threadIdx.x < NBK) {
        int v = h[threadIdx.x];
        if (v) atomicAdd(&cnt196[threadIdx.x], v);
    }
}

__global__ void scan_coarse_kernel(const int* __restrict__ cnt196, int* __restrict__ base196,
                                   int* __restrict__ cursor196, int* __restrict__ rowptr,
                                   int NBK, int N, int E)
{
    __shared__ int buf[256];
    const int tid = threadIdx.x;
    int v = (tid < NBK) ? cnt196[tid] : 0;
    buf[tid] = v;
    __syncthreads();
#pragma unroll
    for (int ofs = 1; ofs < 256; ofs <<= 1) {
        int t = (tid >= ofs) ? buf[tid - ofs] : 0;
        __syncthreads();
        buf[tid] += t;
        __syncthreads();
    }
    if (tid < NBK) {
        int b = buf[tid] - v;
        base196[tid] = b;
        cursor196[tid] = b;
    }
    if (tid == 0) rowptr[N] = E;
}

// two-pass chunked scatter (no register-array scratch): pass1 LDS-hist,
// claim ranges, pass2 re-read (L2-hit) and write packed edges densely.
__global__ __launch_bounds__(256) void scatter_coarse_kernel(
    const int* __restrict__ src, const int* __restrict__ dst,
    int* __restrict__ cursor196, uint* __restrict__ pkg, int E, int NBK)
{
    __shared__ int histL[256];
    __shared__ int baseL[256];
    const int tid = threadIdx.x;
    const int c0  = blockIdx.x * 2048;
    if (tid < NBK) histL[tid] = 0;
    __syncthreads();
#pragma unroll
    for (int k = 0; k < 8; ++k) {
        int idx = c0 + k * 256 + tid;
        if (idx < E) atomicAdd(&histL[dst[idx] >> 8], 1);
    }
    __syncthreads();
    if (tid < NBK) {
        int h = histL[tid];
        baseL[tid] = (h > 0) ? atomicAdd(&cursor196[tid], h) : 0;
        histL[tid] = 0;
    }
    __syncthreads();
#pragma unroll
    for (int k = 0; k < 8; ++k) {
        int idx = c0 + k * 256 + tid;
        if (idx < E) {
            int d = dst[idx];
            int b = d >> 8;
            int pos = baseL[b] + atomicAdd(&histL[b], 1);
            pkg[pos] = ((uint)d << 16) | (uint)(src[idx] & 0xFFFF);
        }
    }
}

__global__ __launch_bounds__(256) void build_fine_kernel(
    const uint* __restrict__ pkg, const int* __restrict__ cnt196,
    const int* __restrict__ base196, int* __restrict__ rowptr,
    float* __restrict__ dinv, ushort* __restrict__ perm, int N)
{
    __shared__ uint   pkL[8192];
    __shared__ ushort outS[8192];
    __shared__ int hist[256];
    __shared__ int buf[256];
    const int b   = blockIdx.x;
    const int tid = threadIdx.x;
    const int base = base196[b];
    int nE = cnt196[b];
    if (nE > 8192) nE = 8192;

    hist[tid] = 0;
    __syncthreads();
    for (int i = tid; i < nE; i += 256) {
        uint pk = pkg[base + i];
        pkL[i] = pk;
        atomicAdd(&hist[(pk >> 16) & 255], 1);
    }
    __syncthreads();

    int cnt = hist[tid];
    buf[tid] = cnt;
    __syncthreads();
#pragma unroll
    for (int ofs = 1; ofs < 256; ofs <<= 1) {
        int t = (tid >= ofs) ? buf[tid - ofs] : 0;
        __syncthreads();
        buf[tid] += t;
        __syncthreads();
    }
    int excl = buf[tid] - cnt;
    int node = b * 256 + tid;
    if (node < N) {
        rowptr[node] = base + excl;
        dinv[node]   = rsqrtf((float)(cnt + 1));   // +1 self-loop
    }
    hist[tid] = excl;
    __syncthreads();
    for (int i = tid; i < nE; i += 256) {
        uint pk = pkL[i];
        int d = (pk >> 16) & 255;
        int pos = atomicAdd(&hist[d], 1);
        outS[pos] = (ushort)(pk & 0xFFFFu);
    }
    __syncthreads();
    for (int i = tid; i < nE; i += 256) perm[base + i] = outS[i];
}

// ------------------------- W fragment prep (bf16 split) ---------------------

template<int K, int NOUT>
static DEV_INLINE void prep_one(const float* __restrict__ W,
                                ushort* __restrict__ Wh, ushort* __restrict__ Wl, int id) {
    constexpr int C = NOUT / 16;
    int lane = id & 63;
    int tc   = id >> 6;
    int c = tc % C, t = tc / C;
    int krow = t * 32 + (lane >> 4) * 8;
    int col  = c * 16 + (lane & 15);
#pragma unroll
    for (int j = 0; j < 8; ++j) {
        float w = W[(size_t)(krow + j) * NOUT + col];
        uint u = __float_as_uint(w);
        Wh[(size_t)id * 8 + j] = (ushort)(u >> 16);
        float r = w - __uint_as_float(u & 0xFFFF0000u);
        Wl[(size_t)id * 8 + j] = (ushort)(__float_as_uint(r) >> 16);
    }
}

__global__ void prep_wfrag_all_kernel(
    const float* __restrict__ W1, const float* __restrict__ W2, const float* __restrict__ W3,
    ushort* w1h, ushort* w1l, ushort* w2h, ushort* w2l, ushort* w3h, ushort* w3l)
{
    int id = blockIdx.x * 256 + threadIdx.x;
    if (id < 2048)       prep_one<128, 128>(W1, w1h, w1l, id);
    else if (id < 3072)  prep_one<128, 64>(W2, w2h, w2l, id - 2048);
    else if (id < 4096)  prep_one<64, 128>(W3, w3h, w3l, id - 3072);
}

// ------------------------------ MFMA GEMM -----------------------------------
// C[N,NOUT] = A[N,K] @ W, with epilogue options:
//   ABF:      A is packed bf16 (2-product)   else f32 hi/lo split (3-product)
//   SCALEDI:  multiply row by dinv[row]
//   POSTB:    add bias_n[col]
//   OUTBF:    pack output to bf16

template<int K, int NOUT, bool ABF, bool SCALEDI, bool POSTB, bool OUTBF>
__global__ __launch_bounds__(256) void gemm_mfma_kernel(
    const void* __restrict__ A, const ushort* __restrict__ Whf, const ushort* __restrict__ Wlf,
    const float* __restrict__ dinv, const float* __restrict__ bias_n,
    void* __restrict__ Cout, int N)
{
    constexpr int C  = NOUT / 16;
    constexpr int T  = K / 32;
    const int tid  = threadIdx.x;
    const int w    = tid >> 6;
    const int lane = tid & 63;
    const int row0 = blockIdx.x * 64 + w * 16;

    const int arow  = row0 + (lane & 15);
    const int arowc = (arow < N) ? arow : (N - 1);
    const int lq    = (lane >> 4);

    const bf16x8* WH = reinterpret_cast<const bf16x8*>(Whf);
    const bf16x8* WL = reinterpret_cast<const bf16x8*>(Wlf);

    f32x4 acc[C];
#pragma unroll
    for (int c = 0; c < C; ++c) acc[c] = (f32x4){0.f, 0.f, 0.f, 0.f};

#pragma unroll
    for (int t = 0; t < T; ++t) {
        bf16x8 ah, al;
        if (ABF) {
            const ushort* ap = (const ushort*)A + (size_t)arowc * K + t * 32 + lq * 8;
            ah = *reinterpret_cast<const bf16x8*>(ap);
        } else {
            const float* ap = (const float*)A + (size_t)arowc * K + t * 32 + lq * 8;
            float4 x0 = *reinterpret_cast<const float4*>(ap);
            float4 x1 = *reinterpret_cast<const float4*>(ap + 4);
            split8(x0, x1, ah, al);
        }
#pragma unroll
        for (int c = 0; c < C; ++c) {
            bf16x8 bh = WH[(t * C + c) * 64 + lane];
            bf16x8 bl = WL[(t * C + c) * 64 + lane];
            acc[c] = __builtin_amdgcn_mfma_f32_16x16x32_bf16(ah, bh, acc[c], 0, 0, 0);
            if (!ABF)
                acc[c] = __builtin_amdgcn_mfma_f32_16x16x32_bf16(al, bh, acc[c], 0, 0, 0);
            acc[c] = __builtin_amdgcn_mfma_f32_16x16x32_bf16(ah, bl, acc[c], 0, 0, 0);
        }
    }

    const int rbase = (lane >> 4) * 4;
    const int ccol  = (lane & 15);
#pragma unroll
    for (int r = 0; r < 4; ++r) {
        int row = row0 + rbase + r;
        if (row < N) {
            float di = SCALEDI ? dinv[row] : 1.0f;
#pragma unroll
            for (int c = 0; c < C; ++c) {
                int col = c * 16 + ccol;
                float v = acc[c][r];
                if (SCALEDI) v *= di;
                if (POSTB)   v += bias_n[col];
                if (OUTBF) ((ushort*)Cout)[(size_t)row * NOUT + col] = (ushort)f2bf_rne(v);
                else       ((float*)Cout)[(size_t)row * NOUT + col] = v;
            }
        }
    }
}

// ------------------------------ gather --------------------------------------
// val = di * (sum_e H'[src_e] + H'[node]);  if RELU: val = relu(val + bias);
// if POSTDI: val *= di.  OUT bf16 or f32.
// GROUP = FW/4 lanes per node (uint4 per lane).

template<int FW, bool RELU, bool POSTDI, bool OUTBF>
__global__ __launch_bounds__(256) void gather_kernel(
    const uint* __restrict__ H, const int* __restrict__ rowptr,
    const ushort* __restrict__ perm, const float* __restrict__ dinv,
    const float* __restrict__ bias, void* __restrict__ OUT, int N)
{
    constexpr int GROUP = FW / 4;
    constexpr int NPB   = 256 / GROUP;
    const int lane = threadIdx.x % GROUP;
    const int g    = threadIdx.x / GROUP;
    const int node = blockIdx.x * NPB + g;
    if (node >= N) return;

    const int beg = rowptr[node];
    const int end = rowptr[node + 1];
    const float di = dinv[node];

    float4 o0 = make_float4(0.f,0.f,0.f,0.f), o1 = o0;
    uint4 sv = reinterpret_cast<const uint4*>(H + (size_t)node * FW)[lane];
    add8(o0, o1, sv);
    gather_sum<FW>(H, perm, beg, end, lane, o0, o1);

    float v[8] = {o0.x, o0.y, o0.z, o0.w, o1.x, o1.y, o1.z, o1.w};
#pragma unroll
    for (int j = 0; j < 8; ++j) v[j] *= di;
    if (RELU) {
        const float* bp = bias + lane * 8;
#pragma unroll
        for (int j = 0; j < 8; ++j) v[j] = fmaxf(v[j] + bp[j], 0.f);
    }
    if (POSTDI) {
#pragma unroll
        for (int j = 0; j < 8; ++j) v[j] *= di;
    }

    if (OUTBF) {
        uint4 u;
        u.x = f2bf_rne(v[0]) | (f2bf_rne(v[1]) << 16);
        u.y = f2bf_rne(v[2]) | (f2bf_rne(v[3]) << 16);
        u.z = f2bf_rne(v[4]) | (f2bf_rne(v[5]) << 16);
        u.w = f2bf_rne(v[6]) | (f2bf_rne(v[7]) << 16);
        reinterpret_cast<uint4*>((uint*)OUT + (size_t)node * FW)[lane] = u;
    } else {
        float4* O = reinterpret_cast<float4*>((float*)OUT + (size_t)node * (FW * 2));
        O[lane * 2]     = make_float4(v[0], v[1], v[2], v[3]);
        O[lane * 2 + 1] = make_float4(v[4], v[5], v[6], v[7]);
    }
}

// ------------------------------- launcher -----------------------------------

static inline size_t align_up(size_t v, size_t a) { return (v + a - 1) / a * a; }

extern "C" void kernel_launch(void* const* d_in, const int* in_sizes, int n_in,
                              void* d_out, int out_size, void* d_ws, size_t ws_size,
                              hipStream_t stream) {
    const float* x  = (const float*)d_in[0];
    const int*   ei = (const int*)d_in[1];
    const float* W1 = (const float*)d_in[2];
    const float* b1 = (const float*)d_in[3];
    const float* W2 = (const float*)d_in[4];
    const float* b2 = (const float*)d_in[5];
    const float* W3 = (const float*)d_in[6];
    const float* b3 = (const float*)d_in[7];
    float* out = (float*)d_out;

    const int N = in_sizes[0] / 128;   // 50000
    const int E = in_sizes[1] / 2;     // 800000
    const int* src = ei;
    const int* dst = ei + E;
    const int NBK = (N + 255) / 256;   // 196 coarse buckets

    // workspace layout
    char* ws = (char*)d_ws;
    size_t off = 0;
    float* dinv      = (float*)(ws + off); off = align_up(off + (size_t)N * 4, 512);
    int*   rowptr    = (int*)  (ws + off); off = align_up(off + (size_t)(N + 1) * 4, 512);
    int*   cnt196    = (int*)  (ws + off); off = align_up(off + (size_t)NBK * 4, 512);
    int*   base196   = (int*)  (ws + off); off = align_up(off + (size_t)NBK * 4, 512);
    int*   cursor196 = (int*)  (ws + off); off = align_up(off + (size_t)NBK * 4, 512);
    ushort* perm     = (ushort*)(ws + off); off = align_up(off + (size_t)E * 2, 512);
    uint*  pkg       = (uint*) (ws + off); off = align_up(off + (size_t)E * 4, 512);
    uint*  regA      = (uint*) (ws + off); off = align_up(off + (size_t)N * 64 * 4, 512);
    uint*  regB      = (uint*) (ws + off); off = align_up(off + (size_t)N * 64 * 4, 512);
    ushort* w1h = (ushort*)(ws + off); off = align_up(off + (size_t)128 * 128 * 2, 512);
    ushort* w1l = (ushort*)(ws + off); off = align_up(off + (size_t)128 * 128 * 2, 512);
    ushort* w2h = (ushort*)(ws + off); off = align_up(off + (size_t)128 * 64 * 2, 512);
    ushort* w2l = (ushort*)(ws + off); off = align_up(off + (size_t)128 * 64 * 2, 512);
    ushort* w3h = (ushort*)(ws + off); off = align_up(off + (size_t)64 * 128 * 2, 512);
    ushort* w3l = (ushort*)(ws + off); off = align_up(off + (size_t)64 * 128 * 2, 512);
    (void)ws_size;

    // buffer reuse:
    uint*  H1bf  = regA;                    // [N,128] bf16
    uint*  AGG1  = regB;                    // [N,128] bf16
    uint*  H2bf  = regA;                    // [N,64] bf16 (H1 dead)
    uint*  H3bf  = regA + (size_t)N * 32;   // [N,64] bf16
    float* T     = (float*)regB;            // [N,64] f32  (AGG1 dead)

    const int TPB = 256;
    dim3 blk(TPB);
    int gRow = (N + 63) / 64;

    // ---- W fragment prep ----
    prep_wfrag_all_kernel<<<16, blk, 0, stream>>>(W1, W2, W3, w1h, w1l, w2h, w2l, w3h, w3l);

    // ---- CSR build ----
    hipMemsetAsync(cnt196, 0, (size_t)NBK * 4, stream);
    hist_coarse_kernel<<<392, blk, 0, stream>>>(dst, cnt196, E, NBK);
    scan_coarse_kernel<<<1, blk, 0, stream>>>(cnt196, base196, cursor196, rowptr, NBK, N, E);
    scatter_coarse_kernel<<<(E + 2047) / 2048, blk, 0, stream>>>(src, dst, cursor196, pkg, E, NBK);
    build_fine_kernel<<<NBK, blk, 0, stream>>>(pkg, cnt196, base196, rowptr, dinv, perm, N);

    // ---- layer pipeline (unfused) ----
    // gemm1: H1' = (x@W1)*di
    gemm_mfma_kernel<128, 128, false, true, false, true><<<gRow, blk, 0, stream>>>(
        x, w1h, w1l, dinv, nullptr, H1bf, N);
    // gather1: AGG1 = relu(di*S(H1') + b1)
    gather_kernel<64, true, false, true><<<(N + 15) / 16, blk, 0, stream>>>(
        H1bf, rowptr, perm, dinv, b1, AGG1, N);
    // gemm2: H2' = (AGG1@W2)*di
    gemm_mfma_kernel<128, 64, true, true, false, true><<<gRow, blk, 0, stream>>>(
        AGG1, w2h, w2l, dinv, nullptr, H2bf, N);
    // gather2: H3' = relu(di*S(H2') + b2)*di
    gather_kernel<32, true, true, true><<<(N + 31) / 32, blk, 0, stream>>>(
        H2bf, rowptr, perm, dinv, b2, H3bf, N);
    // gather3: T = di*S(H3')
    gather_kernel<32, false, false, false><<<(N + 31) / 32, blk, 0, stream>>>(
        H3bf, rowptr, perm, dinv, nullptr, T, N);
    // gemm3: out = T@W3 + b3
    gemm_mfma_kernel<64, 128, false, false, true, false><<<gRow, blk, 0, stream>>>(
        T, w3h, w3l, nullptr, b3, out, N);
}